// Round 14
// baseline (611.338 us; speedup 1.0000x reference)
//
#include <hip/hip_runtime.h>
#include <hip/hip_bf16.h>

namespace {
constexpr int N_NODES = 10000;
constexpr int FIN  = 128;
constexpr int H1S  = 64;
constexpr int H2S  = 32;
constexpr int RREL = 65;
constexpr int EO   = 320000;
constexpr int ES   = 160000;
constexpr int NBR  = 4;
constexpr int BP   = 4096;
constexpr int CAP_MAIN = EO + 128 * RREL;      // 328320
constexpr int CAP_SUB  = ES + 128 * RREL;      // 168320
constexpr int CAP_TOT  = CAP_MAIN + 4 * CAP_SUB;   // 1001600
constexpr int CHK_MAIN = CAP_MAIN / 128;       // 2565
constexpr int CHK_SUB  = CAP_SUB / 128;        // 1315
constexpr int CHK_TOT  = CHK_MAIN + 4 * CHK_SUB;   // 7825
constexpr int CHK_TOT_PAD = 7840;
constexpr int SCH = 1024;
constexpr int SBLK_MAIN = (EO + SCH - 1) / SCH;    // 313
}

typedef unsigned short u16;
typedef unsigned int   u32;
typedef unsigned long long u64;
typedef short bf16x8 __attribute__((ext_vector_type(8)));
typedef float f32x4  __attribute__((ext_vector_type(4)));

__device__ __forceinline__ u16 f2bf(float f) {
    u32 u = __builtin_bit_cast(u32, f);
    u32 r = u + 0x7FFFu + ((u >> 16) & 1u);
    return (u16)(r >> 16);
}
__device__ __forceinline__ float bf2f_lo(u32 v) { return __builtin_bit_cast(float, v << 16); }
__device__ __forceinline__ float bf2f_hi(u32 v) { return __builtin_bit_cast(float, v & 0xFFFF0000u); }
__device__ __forceinline__ bf16x8 as_bf16x8(uint4 v) {
    union { uint4 u; bf16x8 b; } cv; cv.u = v; return cv.b;
}
__device__ __forceinline__ int chunk_graph(int bid) {
    return (bid < CHK_MAIN) ? 0 : 1 + (bid - CHK_MAIN) / CHK_SUB;
}
__device__ __forceinline__ int xcd_swz(int bid) {
    constexpr int q = CHK_TOT / 8, rr = CHK_TOT % 8;
    int x = bid & 7, i = bid >> 3;
    return (x < rr ? x * (q + 1) : rr * (q + 1) + (x - rr) * q) + i;
}

// ---------------- relation histogram (LDS-aggregated) ----------------
__global__ __launch_bounds__(256) void count_hist_all(const int* __restrict__ et_o,
                                                      const int* __restrict__ et_s,
                                                      int* __restrict__ hist) {
    int g = blockIdx.y;
    const int* etv; int E;
    if (g == 0) { etv = et_o; E = EO; }
    else { etv = et_s + (size_t)(g - 1) * ES; E = ES; }
    __shared__ int lh[RREL];
    for (int i = threadIdx.x; i < RREL; i += 256) lh[i] = 0;
    __syncthreads();
    for (int e = blockIdx.x * 256 + threadIdx.x; e < E; e += gridDim.x * 256)
        atomicAdd(&lh[etv[e]], 1);
    __syncthreads();
    for (int i = threadIdx.x; i < RREL; i += 256) {
        int c = lh[i];
        if (c) atomicAdd(&hist[g * RREL + i], c);
    }
}

// ---------------- per-graph padded prefix sum + chunk->relation map ----------------
__global__ void prefix_fill(const int* __restrict__ hist, int* __restrict__ cursor,
                            int* __restrict__ relbase, int* __restrict__ c2r) {
    int g = blockIdx.x;
    __shared__ int offs[RREL + 1];
    int capc  = (g == 0) ? CHK_MAIN : CHK_SUB;
    int cbase = (g == 0) ? 0 : CHK_MAIN + (g - 1) * CHK_SUB;
    int ebase = (g == 0) ? 0 : CAP_MAIN + (g - 1) * CAP_SUB;
    if (threadIdx.x == 0) {
        int acc = 0;
        for (int r = 0; r < RREL; ++r) {
            offs[r] = acc;
            cursor[g * RREL + r]  = ebase + acc;
            relbase[g * RREL + r] = ebase + acc;
            int c = hist[g * RREL + r];
            acc += (c + 127) & ~127;
        }
        offs[RREL] = acc;
    }
    __syncthreads();
    int total = offs[RREL];
    for (int c = threadIdx.x; c < capc; c += blockDim.x) {
        int pos = c * 128;
        int r = -1;
        if (pos < total) {
            int lo = 0, hi = RREL - 1;
            while (lo < hi) { int mid = (lo + hi + 1) >> 1; if (offs[mid] <= pos) lo = mid; else hi = mid - 1; }
            r = lo;
        }
        c2r[cbase + c] = r;
    }
}

// ---------------- relation-sort scatter (temp arrays, arbitrary intra-order) -----
__global__ __launch_bounds__(256) void scatter_rel(const int* __restrict__ ei_o,
                                                   const int* __restrict__ et_o,
                                                   const int* __restrict__ ei_s,
                                                   const int* __restrict__ et_s,
                                                   int* __restrict__ cursor,
                                                   int* __restrict__ ssrcT,
                                                   int* __restrict__ sdstT) {
    int g = blockIdx.y;
    const int* srcv; const int* dstv; const int* etv; int E;
    if (g == 0) { srcv = ei_o; dstv = ei_o + EO; etv = et_o; E = EO; }
    else {
        int b = g - 1;
        srcv = ei_s + (size_t)b * 2 * ES;
        dstv = srcv + ES;
        etv  = et_s + (size_t)b * ES;
        E = ES;
    }
    __shared__ int lh[RREL];
    __shared__ int lbase[RREL];
    int tid = threadIdx.x;
    int e0 = blockIdx.x * SCH;
    if (e0 >= E) return;
    int e1 = min(e0 + SCH, E);
    for (int i = tid; i < RREL; i += 256) lh[i] = 0;
    __syncthreads();
    for (int e = e0 + tid; e < e1; e += 256)
        atomicAdd(&lh[etv[e]], 1);
    __syncthreads();
    for (int i = tid; i < RREL; i += 256) {
        int c = lh[i];
        lbase[i] = c ? atomicAdd(&cursor[g * RREL + i], c) : 0;
        lh[i] = 0;
    }
    __syncthreads();
    for (int e = e0 + tid; e < e1; e += 256) {
        int r = etv[e];
        int rank = atomicAdd(&lh[r], 1);
        int pos = lbase[r] + rank;
        ssrcT[pos] = srcv[e];
        sdstT[pos] = dstv[e];
    }
}

// ---------------- per-(g,r) segment dst histogram in LDS -> deg_r ----------------
__global__ __launch_bounds__(256) void seg_hist(const int* __restrict__ sdstT,
                                                const int* __restrict__ relbase,
                                                const int* __restrict__ hist,
                                                u32* __restrict__ deg_r) {
    int r = blockIdx.x, g = blockIdx.y;
    __shared__ u32 h[N_NODES];
    int tid = threadIdx.x;
    for (int i = tid; i < N_NODES; i += 256) h[i] = 0;
    __syncthreads();
    int start = relbase[g * RREL + r], cnt = hist[g * RREL + r];
    for (int i = start + tid; i < start + cnt; i += 256)
        atomicAdd(&h[sdstT[i]], 1u);
    __syncthreads();
    u32* out = deg_r + (size_t)(g * RREL + r) * N_NODES;
    for (int i = tid; i < N_NODES; i += 256) out[i] = h[i];
}

// ---------------- per-(g,r) prefix over d: base_rel[g][r][d] ----------------
__global__ __launch_bounds__(256) void scan_baserel(const u32* __restrict__ deg_r,
                                                    const int* __restrict__ relbase,
                                                    u32* __restrict__ base_rel) {
    int r = blockIdx.x, g = blockIdx.y;
    const u32* din = deg_r + (size_t)(g * RREL + r) * N_NODES;
    u32* bout = base_rel + (size_t)(g * RREL + r) * N_NODES;
    u32 off = (u32)relbase[g * RREL + r];
    __shared__ u32 part[257];
    int tid = threadIdx.x;
    const int CH = (N_NODES + 255) / 256;
    int base = tid * CH;
    u32 s = 0;
    for (int i = 0; i < CH; ++i) { int ix = base + i; if (ix < N_NODES) s += din[ix]; }
    part[tid + 1] = s;
    if (tid == 0) part[0] = 0;
    __syncthreads();
    if (tid == 0) { for (int i = 1; i <= 256; ++i) part[i] += part[i - 1]; }
    __syncthreads();
    u32 acc = off + part[tid];
    for (int i = 0; i < CH; ++i) {
        int ix = base + i;
        if (ix < N_NODES) { bout[ix] = acc; acc += din[ix]; }
    }
}

// ---------------- per-(g,r) re-sort segment by dst: (r,d)-sorted edges -----------
__global__ __launch_bounds__(256) void resort(const int* __restrict__ ssrcT,
                                              const int* __restrict__ sdstT,
                                              const int* __restrict__ relbase,
                                              const int* __restrict__ hist,
                                              const u32* __restrict__ base_rel,
                                              const u32* __restrict__ deg_r,
                                              int* __restrict__ ssrc2,
                                              float* __restrict__ snrm2) {
    int r = blockIdx.x, g = blockIdx.y;
    int cnt = hist[g * RREL + r];
    if (cnt == 0) return;
    __shared__ u32 cur[N_NODES];
    __shared__ u16 dg[N_NODES];
    int tid = threadIdx.x;
    const u32* bslice = base_rel + (size_t)(g * RREL + r) * N_NODES;
    const u32* dslice = deg_r + (size_t)(g * RREL + r) * N_NODES;
    for (int i = tid; i < N_NODES; i += 256) {
        cur[i] = bslice[i];
        dg[i] = (u16)dslice[i];
    }
    __syncthreads();
    int start = relbase[g * RREL + r];
    for (int pos = start + tid; pos < start + cnt; pos += 256) {
        int d = sdstT[pos];
        u32 slot = atomicAdd(&cur[d], 1u);
        ssrc2[slot] = ssrcT[pos];
        snrm2[slot] = 1.0f / fmaxf((float)dg[d], 1.0f);
    }
}

// ---------------- all dtype-convert preps fused ----------------
namespace {
constexpr int NX_  = 5 * N_NODES * FIN;
constexpr int NW1_ = 5 * RREL * FIN * H1S;
constexpr int NW2_ = 5 * RREL * H1S * H2S;
constexpr int NM1_ = 256 * 576;
constexpr int NM2_ = 128 * 256;
constexpr int NM3_ = 128 * 128;
constexpr int NPREP = NX_ + NW1_ + NW2_ + NM1_ + NM2_ + NM3_;
}
__global__ __launch_bounds__(256) void prep_all(const float* __restrict__ x_o,
                                                const float* __restrict__ x_s,
                                                const float* __restrict__ W1,
                                                const float* __restrict__ Ws1,
                                                const float* __restrict__ W2,
                                                const float* __restrict__ Ws2,
                                                const float* __restrict__ mw1,
                                                const float* __restrict__ mw2,
                                                const float* __restrict__ mw3,
                                                u16* __restrict__ xbf,
                                                u16* __restrict__ wt1,
                                                u16* __restrict__ wt2,
                                                u16* __restrict__ w1t,
                                                u16* __restrict__ w2t,
                                                u16* __restrict__ w3t) {
    int t = blockIdx.x * 256 + threadIdx.x;
    if (t < NX_) {
        int g = t / (N_NODES * FIN), off = t % (N_NODES * FIN);
        float v = (g == 0) ? x_o[off] : x_s[(size_t)(g - 1) * N_NODES * FIN + off];
        xbf[t] = f2bf(v);
        return;
    }
    t -= NX_;
    if (t < NW1_) {
        int q = t % (RREL * FIN * H1S), g = t / (RREL * FIN * H1S);
        int k = q & 127; int ro = q >> 7; int o = ro & 63; int r = ro >> 6;
        const float* src = (g == 0) ? W1 : Ws1 + (size_t)(g - 1) * RREL * FIN * H1S;
        wt1[(size_t)g * RREL * FIN * H1S + q] = f2bf(src[((size_t)r * FIN + k) * H1S + o]);
        return;
    }
    t -= NW1_;
    if (t < NW2_) {
        int q = t % (RREL * H1S * H2S), g = t / (RREL * H1S * H2S);
        int k = q & 63; int ro = q >> 6; int o = ro & 31; int r = ro >> 5;
        const float* src = (g == 0) ? W2 : Ws2 + (size_t)(g - 1) * RREL * H1S * H2S;
        wt2[(size_t)g * RREL * H1S * H2S + q] = f2bf(src[((size_t)r * H1S + k) * H2S + o]);
        return;
    }
    t -= NW2_;
    if (t < NM1_) {
        int k = t % 576, o = t / 576;
        w1t[t] = f2bf(mw1[(size_t)k * 256 + o]);
        return;
    }
    t -= NM1_;
    if (t < NM2_) {
        int k = t % 256, o = t / 256;
        w2t[t] = f2bf(mw2[(size_t)k * 128 + o]);
        return;
    }
    t -= NM2_;
    if (t < NM3_) {
        int k = t % 128, o = t / 128;
        w3t[t] = (o < 65) ? f2bf(mw3[(size_t)k * 65 + o]) : (u16)0;
    }
}

// ---------------- layer-1 MFMA message GEMM ----------------
__global__ __launch_bounds__(256) void rgcn_mfma_l1_all(const u16* __restrict__ xbfa,
                                                        const int* __restrict__ ssrc,
                                                        const float* __restrict__ snrm,
                                                        const int* __restrict__ c2r,
                                                        const u16* __restrict__ wt1a,
                                                        u16* __restrict__ medge) {
    __shared__ uint4 Xs4[128 * 16];
    __shared__ uint4 Wt4[64 * 16];
    int tid = threadIdx.x;
    int bid = xcd_swz(blockIdx.x);
    int r = c2r[bid];
    if (r < 0) return;
    int g = chunk_graph(bid);
    int e0 = bid * 128;
    const u16* xbf = xbfa + (size_t)g * N_NODES * FIN;
    {
        const uint4* wsrc = (const uint4*)(wt1a + ((size_t)g * RREL + r) * H1S * FIN);
        #pragma unroll
        for (int i = 0; i < 4; ++i) {
            int g16 = tid + i * 256;
            int row = g16 >> 4, c = g16 & 15;
            Wt4[row * 16 + (c ^ (row & 7))] = wsrc[g16];
        }
    }
    {
        int rt = tid >> 1, h = tid & 1;
        int s = ssrc[e0 + rt];
        const uint4* src = (const uint4*)(xbf + (size_t)s * FIN) + h * 8;
        #pragma unroll
        for (int j = 0; j < 8; ++j) {
            int c = h * 8 + j;
            Xs4[rt * 16 + (c ^ (rt & 7))] = src[j];
        }
    }
    __syncthreads();
    int w = tid >> 6, l = tid & 63;
    int lo = l & 15, hi = l >> 4;
    f32x4 acc[2][4];
    #pragma unroll
    for (int m = 0; m < 2; ++m)
        #pragma unroll
        for (int n = 0; n < 4; ++n) acc[m][n] = {0.f, 0.f, 0.f, 0.f};
    #pragma unroll
    for (int kk = 0; kk < 4; ++kk) {
        int kc = kk * 4 + hi;
        int ea = w * 32 + lo, eb = ea + 16;
        bf16x8 a0 = as_bf16x8(Xs4[ea * 16 + (kc ^ (ea & 7))]);
        bf16x8 a1 = as_bf16x8(Xs4[eb * 16 + (kc ^ (eb & 7))]);
        #pragma unroll
        for (int n = 0; n < 4; ++n) {
            int o = n * 16 + lo;
            bf16x8 b = as_bf16x8(Wt4[o * 16 + (kc ^ (o & 7))]);
            acc[0][n] = __builtin_amdgcn_mfma_f32_16x16x32_bf16(a0, b, acc[0][n], 0, 0, 0);
            acc[1][n] = __builtin_amdgcn_mfma_f32_16x16x32_bf16(a1, b, acc[1][n], 0, 0, 0);
        }
    }
    #pragma unroll
    for (int m = 0; m < 2; ++m) {
        #pragma unroll
        for (int rg = 0; rg < 4; ++rg) {
            int erow = e0 + w * 32 + m * 16 + hi * 4 + rg;
            float nv = snrm[erow];
            if (nv != 0.f) {
                size_t jb = (size_t)erow * H1S;
                #pragma unroll
                for (int n = 0; n < 4; ++n)
                    medge[jb + n * 16 + lo] = f2bf(acc[m][n][rg] * nv);
            }
        }
    }
}

// ---------------- layer-2 MFMA message GEMM ----------------
__global__ __launch_bounds__(256) void rgcn_mfma_l2_all(const u16* __restrict__ h1bfa,
                                                        const int* __restrict__ ssrc,
                                                        const float* __restrict__ snrm,
                                                        const int* __restrict__ c2r,
                                                        const u16* __restrict__ wt2a,
                                                        u16* __restrict__ medge) {
    __shared__ uint4 Xs4[128 * 8];
    __shared__ uint4 Wt4[32 * 8];
    int tid = threadIdx.x;
    int bid = xcd_swz(blockIdx.x);
    int r = c2r[bid];
    if (r < 0) return;
    int g = chunk_graph(bid);
    int e0 = bid * 128;
    const u16* h1bf = h1bfa + (size_t)g * N_NODES * H1S;
    {
        const uint4* wsrc = (const uint4*)(wt2a + ((size_t)g * RREL + r) * H2S * H1S);
        int row = tid >> 3, c = tid & 7;
        Wt4[row * 8 + (c ^ (row & 7))] = wsrc[tid];
    }
    {
        int rt = tid >> 1, h = tid & 1;
        int s = ssrc[e0 + rt];
        const uint4* src = (const uint4*)(h1bf + (size_t)s * H1S) + h * 4;
        #pragma unroll
        for (int j = 0; j < 4; ++j) {
            int c = h * 4 + j;
            Xs4[rt * 8 + (c ^ (rt & 7))] = src[j];
        }
    }
    __syncthreads();
    int w = tid >> 6, l = tid & 63;
    int lo = l & 15, hi = l >> 4;
    f32x4 acc[2][2];
    #pragma unroll
    for (int m = 0; m < 2; ++m)
        #pragma unroll
        for (int n = 0; n < 2; ++n) acc[m][n] = {0.f, 0.f, 0.f, 0.f};
    #pragma unroll
    for (int kk = 0; kk < 2; ++kk) {
        int kc = kk * 4 + hi;
        int ea = w * 32 + lo, eb = ea + 16;
        bf16x8 a0 = as_bf16x8(Xs4[ea * 8 + (kc ^ (ea & 7))]);
        bf16x8 a1 = as_bf16x8(Xs4[eb * 8 + (kc ^ (eb & 7))]);
        #pragma unroll
        for (int n = 0; n < 2; ++n) {
            int o = n * 16 + lo;
            bf16x8 b = as_bf16x8(Wt4[o * 8 + (kc ^ (o & 7))]);
            acc[0][n] = __builtin_amdgcn_mfma_f32_16x16x32_bf16(a0, b, acc[0][n], 0, 0, 0);
            acc[1][n] = __builtin_amdgcn_mfma_f32_16x16x32_bf16(a1, b, acc[1][n], 0, 0, 0);
        }
    }
    #pragma unroll
    for (int m = 0; m < 2; ++m) {
        #pragma unroll
        for (int rg = 0; rg < 4; ++rg) {
            int erow = e0 + w * 32 + m * 16 + hi * 4 + rg;
            float nv = snrm[erow];
            if (nv != 0.f) {
                size_t jb = (size_t)erow * H2S;
                #pragma unroll
                for (int n = 0; n < 2; ++n)
                    medge[jb + n * 16 + lo] = f2bf(acc[m][n][rg] * nv);
            }
        }
    }
}

// ---------------- fused gather + finish, layer 1 (per-relation run gather) -------
__global__ __launch_bounds__(256) void finish_l1_all(const float* __restrict__ x_o,
                                                     const float* __restrict__ x_s,
                                                     const float* __restrict__ root1,
                                                     const float* __restrict__ roots1,
                                                     const float* __restrict__ b1,
                                                     const float* __restrict__ bs1,
                                                     const u16* __restrict__ medge,
                                                     const u32* __restrict__ base_rel,
                                                     const u32* __restrict__ deg_r,
                                                     float* __restrict__ aggH1,
                                                     u16* __restrict__ h1bfa) {
    int g = blockIdx.y;
    const float* x    = (g == 0) ? x_o : x_s + (size_t)(g - 1) * N_NODES * FIN;
    const float* root = (g == 0) ? root1 : roots1 + (size_t)(g - 1) * FIN * H1S;
    const float* bias = (g == 0) ? b1 : bs1 + (size_t)(g - 1) * H1S;
    const u32* br = base_rel + (size_t)g * RREL * N_NODES;
    const u32* dr = deg_r + (size_t)g * RREL * N_NODES;
    float* h1 = aggH1 + (size_t)g * N_NODES * H1S;
    u16* h1bf = h1bfa + (size_t)g * N_NODES * H1S;
    __shared__ float xs[16][FIN + 1];
    int tid = threadIdx.x;
    int vsub = tid >> 4, og = tid & 15;
    int v = blockIdx.x * 16 + vsub;
    bool valid = v < N_NODES;
    int vv = valid ? v : N_NODES - 1;
    #pragma unroll
    for (int i = 0; i < 8; ++i)
        xs[vsub][og + 16 * i] = x[(size_t)vv * FIN + og + 16 * i];
    float4 acc;
    acc.x = bias[og * 4 + 0]; acc.y = bias[og * 4 + 1];
    acc.z = bias[og * 4 + 2]; acc.w = bias[og * 4 + 3];
    for (int r = 0; r < RREL; ++r) {
        u32 base = br[(size_t)r * N_NODES + vv];
        u32 dg   = dr[(size_t)r * N_NODES + vv];
        const u16* mp = medge + (size_t)base * H1S + og * 4;
        for (u32 j = 0; j < dg; ++j) {
            u64 m = __builtin_nontemporal_load((const u64*)(mp + (size_t)j * H1S));
            u32 mlo = (u32)m, mhi = (u32)(m >> 32);
            acc.x += bf2f_lo(mlo); acc.y += bf2f_hi(mlo);
            acc.z += bf2f_lo(mhi); acc.w += bf2f_hi(mhi);
        }
    }
    __syncthreads();
    const float* Rp = root + og * 4;
    #pragma unroll 16
    for (int i = 0; i < FIN; ++i) {
        float xv = xs[vsub][i];
        float4 w = *(const float4*)(Rp + (size_t)i * H1S);
        acc.x += xv * w.x; acc.y += xv * w.y; acc.z += xv * w.z; acc.w += xv * w.w;
    }
    if (valid) {
        float r0 = fmaxf(acc.x, 0.f), r1 = fmaxf(acc.y, 0.f);
        float r2 = fmaxf(acc.z, 0.f), r3 = fmaxf(acc.w, 0.f);
        float* ag = h1 + (size_t)vv * H1S + og * 4;
        ag[0] = r0; ag[1] = r1; ag[2] = r2; ag[3] = r3;
        uint2 pk;
        pk.x = (u32)f2bf(r0) | ((u32)f2bf(r1) << 16);
        pk.y = (u32)f2bf(r2) | ((u32)f2bf(r3) << 16);
        *(uint2*)(h1bf + (size_t)vv * H1S + og * 4) = pk;
    }
}

// ---------------- fused gather + finish, layer 2 (per-relation run gather) -------
__global__ __launch_bounds__(256) void finish_l2_all(const float* __restrict__ aggH1,
                                                     const float* __restrict__ root2,
                                                     const float* __restrict__ roots2,
                                                     const float* __restrict__ b2,
                                                     const float* __restrict__ bs2,
                                                     const u16* __restrict__ medge,
                                                     const u32* __restrict__ base_rel,
                                                     const u32* __restrict__ deg_r,
                                                     float* __restrict__ aggH2) {
    int g = blockIdx.y;
    const float* x    = aggH1 + (size_t)g * N_NODES * H1S;
    const float* root = (g == 0) ? root2 : roots2 + (size_t)(g - 1) * H1S * H2S;
    const float* bias = (g == 0) ? b2 : bs2 + (size_t)(g - 1) * H2S;
    const u32* br = base_rel + (size_t)g * RREL * N_NODES;
    const u32* dr = deg_r + (size_t)g * RREL * N_NODES;
    float* x2 = aggH2 + (size_t)g * N_NODES * H2S;
    __shared__ float xs[32][H1S + 1];
    int tid = threadIdx.x;
    int vsub = tid >> 3, og = tid & 7;
    int v = blockIdx.x * 32 + vsub;
    bool valid = v < N_NODES;
    int vv = valid ? v : N_NODES - 1;
    #pragma unroll
    for (int i = 0; i < 8; ++i)
        xs[vsub][og + 8 * i] = x[(size_t)vv * H1S + og + 8 * i];
    float4 acc;
    acc.x = bias[og * 4 + 0]; acc.y = bias[og * 4 + 1];
    acc.z = bias[og * 4 + 2]; acc.w = bias[og * 4 + 3];
    for (int r = 0; r < RREL; ++r) {
        u32 base = br[(size_t)r * N_NODES + vv];
        u32 dg   = dr[(size_t)r * N_NODES + vv];
        const u16* mp = medge + (size_t)base * H2S + og * 4;
        for (u32 j = 0; j < dg; ++j) {
            u64 m = __builtin_nontemporal_load((const u64*)(mp + (size_t)j * H2S));
            u32 mlo = (u32)m, mhi = (u32)(m >> 32);
            acc.x += bf2f_lo(mlo); acc.y += bf2f_hi(mlo);
            acc.z += bf2f_lo(mhi); acc.w += bf2f_hi(mhi);
        }
    }
    __syncthreads();
    const float* Rp = root + og * 4;
    #pragma unroll
    for (int i = 0; i < H1S; ++i) {
        float xv = xs[vsub][i];
        float4 w = *(const float4*)(Rp + (size_t)i * H2S);
        acc.x += xv * w.x; acc.y += xv * w.y; acc.z += xv * w.z; acc.w += xv * w.w;
    }
    if (valid) {
        float* ag = x2 + (size_t)vv * H2S + og * 4;
        ag[0] = acc.x; ag[1] = acc.y; ag[2] = acc.z; ag[3] = acc.w;
    }
}

// ---------------- gather pair features -> bf16 ----------------
__global__ __launch_bounds__(256) void gather_feats_direct(const float* __restrict__ aggH2,
                                                           const float* __restrict__ features1,
                                                           const int* __restrict__ idx,
                                                           u16* __restrict__ featsbf) {
    int t = blockIdx.x * blockDim.x + threadIdx.x;
    if (t >= BP * 576) return;
    int b = t / 576, c = t % 576;
    int d1 = idx[b], d2 = idx[BP + b];
    float v;
    if (c < 160) {
        int bb = c >> 5, cc = c & 31;
        v = aggH2[(size_t)bb * N_NODES * H2S + (size_t)d1 * H2S + cc];
    } else if (c < 288) {
        v = features1[(size_t)d1 * FIN + (c - 160)];
    } else if (c < 448) {
        int cc2 = c - 288;
        int bb = cc2 >> 5, cc = cc2 & 31;
        v = aggH2[(size_t)bb * N_NODES * H2S + (size_t)d2 * H2S + cc];
    } else {
        v = features1[(size_t)d2 * FIN + (c - 448)];
    }
    featsbf[t] = f2bf(v);
}

// ---------------- MLP MFMA GEMM ----------------
template <int ACT, int OUTF>
__global__ __launch_bounds__(256) void mlp_mfma(const u16* __restrict__ A,
                                                const u16* __restrict__ Bt,
                                                const float* __restrict__ bias,
                                                u16* __restrict__ Cbf,
                                                float* __restrict__ Cf,
                                                int M, int N, int K) {
    __shared__ uint4 As4[128 * 8];
    __shared__ uint4 Bs4[64 * 8];
    int tid = threadIdx.x;
    int row0 = blockIdx.x * 128, col0 = blockIdx.y * 64;
    int w = tid >> 6, l = tid & 63;
    int lo = l & 15, hi = l >> 4;
    f32x4 acc[2][4];
    #pragma unroll
    for (int m = 0; m < 2; ++m)
        #pragma unroll
        for (int n = 0; n < 4; ++n) acc[m][n] = {0.f, 0.f, 0.f, 0.f};
    int nchunks = K >> 6;
    for (int ch = 0; ch < nchunks; ++ch) {
        #pragma unroll
        for (int i = 0; i < 4; ++i) {
            int g16 = tid + i * 256;
            int rr = g16 >> 3, c = g16 & 7;
            As4[rr * 8 + (c ^ (rr & 7))] =
                *((const uint4*)(A + (size_t)(row0 + rr) * K + ch * 64) + c);
        }
        #pragma unroll
        for (int i = 0; i < 2; ++i) {
            int g16 = tid + i * 256;
            int rr = g16 >> 3, c = g16 & 7;
            Bs4[rr * 8 + (c ^ (rr & 7))] =
                *((const uint4*)(Bt + (size_t)(col0 + rr) * K + ch * 64) + c);
        }
        __syncthreads();
        #pragma unroll
        for (int ks = 0; ks < 2; ++ks) {
            int kc = ks * 4 + hi;
            int ra = w * 32 + lo, rb = w * 32 + 16 + lo;
            bf16x8 a0 = as_bf16x8(As4[ra * 8 + (kc ^ (ra & 7))]);
            bf16x8 a1 = as_bf16x8(As4[rb * 8 + (kc ^ (rb & 7))]);
            #pragma unroll
            for (int n = 0; n < 4; ++n) {
                int o = n * 16 + lo;
                bf16x8 b = as_bf16x8(Bs4[o * 8 + (kc ^ (o & 7))]);
                acc[0][n] = __builtin_amdgcn_mfma_f32_16x16x32_bf16(a0, b, acc[0][n], 0, 0, 0);
                acc[1][n] = __builtin_amdgcn_mfma_f32_16x16x32_bf16(a1, b, acc[1][n], 0, 0, 0);
            }
        }
        __syncthreads();
    }
    #pragma unroll
    for (int m = 0; m < 2; ++m) {
        #pragma unroll
        for (int rg = 0; rg < 4; ++rg) {
            int rr = row0 + w * 32 + m * 16 + hi * 4 + rg;
            if (rr < M) {
                #pragma unroll
                for (int n = 0; n < 4; ++n) {
                    int cc = col0 + n * 16 + lo;
                    if (cc < N) {
                        float v = acc[m][n][rg] + bias[cc];
                        if (ACT == 1) v = (v > 0.f) ? v : expm1f(v);
                        if (OUTF) Cf[(size_t)rr * N + cc] = v;
                        else Cbf[(size_t)rr * N + cc] = f2bf(v);
                    }
                }
            }
        }
    }
}

extern "C" void kernel_launch(void* const* d_in, const int* in_sizes, int n_in,
                              void* d_out, int out_size, void* d_ws, size_t ws_size,
                              hipStream_t stream) {
    const float* x_o      = (const float*)d_in[0];
    const int*   ei_o     = (const int*)d_in[1];
    const int*   et_o     = (const int*)d_in[2];
    const float* x_s      = (const float*)d_in[3];
    const int*   ei_s     = (const int*)d_in[4];
    const int*   et_s     = (const int*)d_in[5];
    const int*   idx      = (const int*)d_in[6];
    const float* features1= (const float*)d_in[7];
    const float* W1       = (const float*)d_in[8];
    const float* root1    = (const float*)d_in[9];
    const float* b1       = (const float*)d_in[10];
    const float* W2       = (const float*)d_in[11];
    const float* root2    = (const float*)d_in[12];
    const float* b2       = (const float*)d_in[13];
    const float* Ws1      = (const float*)d_in[14];
    const float* roots1   = (const float*)d_in[15];
    const float* bs1      = (const float*)d_in[16];
    const float* Ws2      = (const float*)d_in[17];
    const float* roots2   = (const float*)d_in[18];
    const float* bs2      = (const float*)d_in[19];
    const float* mlp_w1   = (const float*)d_in[20];
    const float* mlp_b1   = (const float*)d_in[21];
    const float* mlp_w2   = (const float*)d_in[22];
    const float* mlp_b2   = (const float*)d_in[23];
    const float* mlp_w3   = (const float*)d_in[24];
    const float* mlp_b3   = (const float*)d_in[25];

    // ---- workspace layout (zeroed region FIRST) ----
    int*   hist     = (int*)d_ws;                                // 5*R      [zero]
    int*   ssrc2    = hist + 5 * RREL;                           // CAP_TOT  [zero]
    float* snrm2    = (float*)(ssrc2 + CAP_TOT);                 // CAP_TOT  [zero]
    // ---- end zero region ----
    int*   ssrcT    = (int*)(snrm2 + CAP_TOT);                   // CAP_TOT
    int*   sdstT    = ssrcT + CAP_TOT;                           // CAP_TOT
    int*   cursor   = sdstT + CAP_TOT;                           // 5*R
    int*   relbase  = cursor + 5 * RREL;                         // 5*R
    int*   c2r      = relbase + 5 * RREL;                        // CHK_TOT_PAD
    u32*   deg_r    = (u32*)(c2r + CHK_TOT_PAD);                 // 5*R*N
    u32*   base_rel = deg_r + (size_t)5 * RREL * N_NODES;        // 5*R*N
    float* aggH1    = (float*)(base_rel + (size_t)5 * RREL * N_NODES); // 5*N*64
    float* aggH2    = aggH1 + (size_t)5 * N_NODES * H1S;         // 5*N*32
    u16*   featsbf  = (u16*)(aggH2 + (size_t)5 * N_NODES * H2S); // B*576
    u16*   mh1bf    = featsbf + (size_t)BP * 576;                // B*256
    u16*   mh2bf    = mh1bf + (size_t)BP * 256;                  // B*128
    u16*   w1t      = mh2bf + (size_t)BP * 128;                  // 256*576
    u16*   w2t      = w1t + (size_t)256 * 576;                   // 128*256
    u16*   w3t      = w2t + (size_t)128 * 256;                   // 128*128
    u16*   wt1a     = w3t + (size_t)128 * 128;                   // 5*R*64*128
    u16*   wt2a     = wt1a + (size_t)5 * RREL * H1S * FIN;       // 5*R*32*64
    u16*   xbfa     = wt2a + (size_t)5 * RREL * H2S * H1S;       // 5*N*128
    u16*   h1bfa    = xbfa + (size_t)5 * N_NODES * FIN;          // 5*N*64
    u16*   medge    = h1bfa + (size_t)5 * N_NODES * H1S;         // CAP_TOT*64

    size_t zero_bytes = (size_t)((char*)ssrcT - (char*)d_ws);
    hipMemsetAsync(d_ws, 0, zero_bytes, stream);

    // ---- preprocessing ----
    prep_all<<<(NPREP + 255) / 256, 256, 0, stream>>>(
        x_o, x_s, W1, Ws1, W2, Ws2, mlp_w1, mlp_w2, mlp_w3,
        xbfa, wt1a, wt2a, w1t, w2t, w3t);
    count_hist_all<<<dim3(128, 5), 256, 0, stream>>>(et_o, et_s, hist);
    prefix_fill<<<5, 256, 0, stream>>>(hist, cursor, relbase, c2r);
    scatter_rel<<<dim3(SBLK_MAIN, 5), 256, 0, stream>>>(
        ei_o, et_o, ei_s, et_s, cursor, ssrcT, sdstT);
    seg_hist<<<dim3(RREL, 5), 256, 0, stream>>>(sdstT, relbase, hist, deg_r);
    scan_baserel<<<dim3(RREL, 5), 256, 0, stream>>>(deg_r, relbase, base_rel);
    resort<<<dim3(RREL, 5), 256, 0, stream>>>(
        ssrcT, sdstT, relbase, hist, base_rel, deg_r, ssrc2, snrm2);

    // ---- encoders ----
    rgcn_mfma_l1_all<<<CHK_TOT, 256, 0, stream>>>(
        xbfa, ssrc2, snrm2, c2r, wt1a, medge);
    finish_l1_all<<<dim3((N_NODES + 15) / 16, 5), 256, 0, stream>>>(
        x_o, x_s, root1, roots1, b1, bs1, medge, base_rel, deg_r, aggH1, h1bfa);
    rgcn_mfma_l2_all<<<CHK_TOT, 256, 0, stream>>>(
        h1bfa, ssrc2, snrm2, c2r, wt2a, medge);
    finish_l2_all<<<dim3((N_NODES + 31) / 32, 5), 256, 0, stream>>>(
        aggH1, root2, roots2, b2, bs2, medge, base_rel, deg_r, aggH2);

    // ---- head ----
    gather_feats_direct<<<(BP * 576 + 255) / 256, 256, 0, stream>>>(aggH2, features1, idx, featsbf);
    mlp_mfma<1, 0><<<dim3(BP / 128, 4), 256, 0, stream>>>(featsbf, w1t, mlp_b1, mh1bf, nullptr, BP, 256, 576);
    mlp_mfma<1, 0><<<dim3(BP / 128, 2), 256, 0, stream>>>(mh1bf, w2t, mlp_b2, mh2bf, nullptr, BP, 128, 256);
    mlp_mfma<0, 1><<<dim3(BP / 128, 2), 256, 0, stream>>>(mh2bf, w3t, mlp_b3, nullptr, (float*)d_out, BP, 65, 128);
}

// Round 15
// 419.158 us; speedup vs baseline: 1.4585x; 1.4585x over previous
//
#include <hip/hip_runtime.h>
#include <hip/hip_bf16.h>

namespace {
constexpr int N_NODES = 10000;
constexpr int FIN  = 128;
constexpr int H1S  = 64;
constexpr int H2S  = 32;
constexpr int RREL = 65;
constexpr int EO   = 320000;
constexpr int ES   = 160000;
constexpr int NBR  = 4;
constexpr int BP   = 4096;
constexpr int E_TOT = EO + 4 * ES;             // 960000
constexpr int CAP_MAIN = EO + 128 * RREL;      // 328320
constexpr int CAP_SUB  = ES + 128 * RREL;      // 168320
constexpr int CAP_TOT  = CAP_MAIN + 4 * CAP_SUB;   // 1001600
constexpr int CHK_MAIN = CAP_MAIN / 128;       // 2565
constexpr int CHK_SUB  = CAP_SUB / 128;        // 1315
constexpr int CHK_TOT  = CHK_MAIN + 4 * CHK_SUB;   // 7825
constexpr int CHK_TOT_PAD = 7840;
constexpr int SCH = 1024;
constexpr int SBLK_MAIN = (EO + SCH - 1) / SCH;    // 313
}

typedef unsigned short u16;
typedef unsigned int   u32;
typedef unsigned long long u64;
typedef short bf16x8 __attribute__((ext_vector_type(8)));
typedef float f32x4  __attribute__((ext_vector_type(4)));

__device__ __forceinline__ u16 f2bf(float f) {
    u32 u = __builtin_bit_cast(u32, f);
    u32 r = u + 0x7FFFu + ((u >> 16) & 1u);
    return (u16)(r >> 16);
}
__device__ __forceinline__ float bf2f_lo(u32 v) { return __builtin_bit_cast(float, v << 16); }
__device__ __forceinline__ float bf2f_hi(u32 v) { return __builtin_bit_cast(float, v & 0xFFFF0000u); }
__device__ __forceinline__ bf16x8 as_bf16x8(uint4 v) {
    union { uint4 u; bf16x8 b; } cv; cv.u = v; return cv.b;
}
__device__ __forceinline__ int chunk_graph(int bid) {
    return (bid < CHK_MAIN) ? 0 : 1 + (bid - CHK_MAIN) / CHK_SUB;
}
__device__ __forceinline__ int xcd_swz(int bid) {
    constexpr int q = CHK_TOT / 8, rr = CHK_TOT % 8;
    int x = bid & 7, i = bid >> 3;
    return (x < rr ? x * (q + 1) : rr * (q + 1) + (x - rr) * q) + i;
}

// ---------------- relation histogram (LDS-aggregated) ----------------
__global__ __launch_bounds__(256) void count_hist_all(const int* __restrict__ et_o,
                                                      const int* __restrict__ et_s,
                                                      int* __restrict__ hist) {
    int g = blockIdx.y;
    const int* etv; int E;
    if (g == 0) { etv = et_o; E = EO; }
    else { etv = et_s + (size_t)(g - 1) * ES; E = ES; }
    __shared__ int lh[RREL];
    for (int i = threadIdx.x; i < RREL; i += 256) lh[i] = 0;
    __syncthreads();
    for (int e = blockIdx.x * 256 + threadIdx.x; e < E; e += gridDim.x * 256)
        atomicAdd(&lh[etv[e]], 1);
    __syncthreads();
    for (int i = threadIdx.x; i < RREL; i += 256) {
        int c = lh[i];
        if (c) atomicAdd(&hist[g * RREL + i], c);
    }
}

// ---------------- per-graph padded prefix sum + chunk->relation map ----------------
__global__ void prefix_fill(const int* __restrict__ hist, int* __restrict__ cursor,
                            int* __restrict__ relbase, int* __restrict__ c2r) {
    int g = blockIdx.x;
    __shared__ int offs[RREL + 1];
    int capc  = (g == 0) ? CHK_MAIN : CHK_SUB;
    int cbase = (g == 0) ? 0 : CHK_MAIN + (g - 1) * CHK_SUB;
    int ebase = (g == 0) ? 0 : CAP_MAIN + (g - 1) * CAP_SUB;
    if (threadIdx.x == 0) {
        int acc = 0;
        for (int r = 0; r < RREL; ++r) {
            offs[r] = acc;
            cursor[g * RREL + r]  = ebase + acc;
            relbase[g * RREL + r] = ebase + acc;
            int c = hist[g * RREL + r];
            acc += (c + 127) & ~127;
        }
        offs[RREL] = acc;
    }
    __syncthreads();
    int total = offs[RREL];
    for (int c = threadIdx.x; c < capc; c += blockDim.x) {
        int pos = c * 128;
        int r = -1;
        if (pos < total) {
            int lo = 0, hi = RREL - 1;
            while (lo < hi) { int mid = (lo + hi + 1) >> 1; if (offs[mid] <= pos) lo = mid; else hi = mid - 1; }
            r = lo;
        }
        c2r[cbase + c] = r;
    }
}

// ---------------- relation-sort scatter: ssrc + sdst only ----------------
__global__ __launch_bounds__(256) void scatter_rel(const int* __restrict__ ei_o,
                                                   const int* __restrict__ et_o,
                                                   const int* __restrict__ ei_s,
                                                   const int* __restrict__ et_s,
                                                   int* __restrict__ cursor,
                                                   int* __restrict__ ssrc,
                                                   int* __restrict__ sdst) {
    int g = blockIdx.y;
    const int* srcv; const int* dstv; const int* etv; int E;
    if (g == 0) { srcv = ei_o; dstv = ei_o + EO; etv = et_o; E = EO; }
    else {
        int b = g - 1;
        srcv = ei_s + (size_t)b * 2 * ES;
        dstv = srcv + ES;
        etv  = et_s + (size_t)b * ES;
        E = ES;
    }
    __shared__ int lh[RREL];
    __shared__ int lbase[RREL];
    int tid = threadIdx.x;
    int e0 = blockIdx.x * SCH;
    if (e0 >= E) return;
    int e1 = min(e0 + SCH, E);
    for (int i = tid; i < RREL; i += 256) lh[i] = 0;
    __syncthreads();
    for (int e = e0 + tid; e < e1; e += 256)
        atomicAdd(&lh[etv[e]], 1);
    __syncthreads();
    for (int i = tid; i < RREL; i += 256) {
        int c = lh[i];
        lbase[i] = c ? atomicAdd(&cursor[g * RREL + i], c) : 0;
        lh[i] = 0;
    }
    __syncthreads();
    for (int e = e0 + tid; e < e1; e += 256) {
        int r = etv[e];
        int rank = atomicAdd(&lh[r], 1);
        int pos = lbase[r] + rank;
        ssrc[pos] = srcv[e];
        sdst[pos] = dstv[e];
    }
}

// ---------------- per-(g,r) segment dst histogram in LDS -> deg_r ----------------
__global__ __launch_bounds__(256) void seg_hist(const int* __restrict__ sdst,
                                                const int* __restrict__ relbase,
                                                const int* __restrict__ hist,
                                                u32* __restrict__ deg_r) {
    int r = blockIdx.x, g = blockIdx.y;
    __shared__ u32 h[N_NODES];
    int tid = threadIdx.x;
    for (int i = tid; i < N_NODES; i += 256) h[i] = 0;
    __syncthreads();
    int start = relbase[g * RREL + r], cnt = hist[g * RREL + r];
    for (int i = start + tid; i < start + cnt; i += 256)
        atomicAdd(&h[sdst[i]], 1u);
    __syncthreads();
    u32* out = deg_r + (size_t)(g * RREL + r) * N_NODES;
    for (int i = tid; i < N_NODES; i += 256) out[i] = h[i];
}

// ---------------- node_deg[g][d] = sum_r deg_r ----------------
__global__ __launch_bounds__(256) void nodedeg_from_degr(const u32* __restrict__ deg_r,
                                                         int* __restrict__ node_deg) {
    int t = blockIdx.x * 256 + threadIdx.x;
    if (t >= 5 * N_NODES) return;
    int g = t / N_NODES, d = t % N_NODES;
    const u32* base = deg_r + (size_t)g * RREL * N_NODES + d;
    u32 s = 0;
    for (int r = 0; r < RREL; ++r) s += base[(size_t)r * N_NODES];
    node_deg[t] = (int)s;
}

// ---------------- per-graph row_ptr scan (absolute slot space) ----------------
__global__ __launch_bounds__(256) void scan_rowptr(const int* __restrict__ node_deg,
                                                   int* __restrict__ row_ptr) {
    int g = blockIdx.x;
    const int* nd = node_deg + (size_t)g * N_NODES;
    int* rp = row_ptr + (size_t)g * (N_NODES + 1);
    int off = (g == 0) ? 0 : EO + (g - 1) * ES;
    __shared__ int part[257];
    int tid = threadIdx.x;
    const int CH = (N_NODES + 255) / 256;
    int base = tid * CH;
    int s = 0;
    for (int i = 0; i < CH; ++i) { int ix = base + i; if (ix < N_NODES) s += nd[ix]; }
    part[tid + 1] = s;
    if (tid == 0) part[0] = 0;
    __syncthreads();
    if (tid == 0) { for (int i = 1; i <= 256; ++i) part[i] += part[i - 1]; }
    __syncthreads();
    int acc = part[tid];
    for (int i = 0; i < CH; ++i) {
        int ix = base + i;
        if (ix < N_NODES) { rp[ix] = off + acc; acc += nd[ix]; }
    }
    if (tid == 0) rp[N_NODES] = off + part[256];
}

// ---------------- base_abs[g][r][d] = row_ptr[g][d] + prefix_r deg_r ----------------
__global__ __launch_bounds__(256) void drbase(const u32* __restrict__ deg_r,
                                              const int* __restrict__ row_ptr,
                                              u32* __restrict__ base_abs) {
    int t = blockIdx.x * 256 + threadIdx.x;
    if (t >= 5 * N_NODES) return;
    int g = t / N_NODES, d = t % N_NODES;
    u32 run = (u32)row_ptr[(size_t)g * (N_NODES + 1) + d];
    const u32* din = deg_r + (size_t)g * RREL * N_NODES + d;
    u32* bout = base_abs + (size_t)g * RREL * N_NODES + d;
    for (int r = 0; r < RREL; ++r) {
        bout[(size_t)r * N_NODES] = run;
        run += din[(size_t)r * N_NODES];
    }
}

// ---------------- per-(g,r): INVERSE map eidx[slot]=pos + snrm[pos] ----------------
__global__ __launch_bounds__(256) void snrm_eidx(const int* __restrict__ sdst,
                                                 const int* __restrict__ relbase,
                                                 const int* __restrict__ hist,
                                                 const u32* __restrict__ base_abs,
                                                 const u32* __restrict__ deg_r,
                                                 int* __restrict__ eidx,
                                                 float* __restrict__ snrm) {
    int r = blockIdx.x, g = blockIdx.y;
    int cnt = hist[g * RREL + r];
    if (cnt == 0) return;
    __shared__ u32 cur[N_NODES];
    __shared__ u16 dg[N_NODES];
    int tid = threadIdx.x;
    const u32* bslice = base_abs + (size_t)(g * RREL + r) * N_NODES;
    const u32* dslice = deg_r + (size_t)(g * RREL + r) * N_NODES;
    for (int i = tid; i < N_NODES; i += 256) {
        cur[i] = bslice[i];
        dg[i] = (u16)dslice[i];
    }
    __syncthreads();
    int start = relbase[g * RREL + r];
    for (int pos = start + tid; pos < start + cnt; pos += 256) {
        int d = sdst[pos];
        u32 slot = atomicAdd(&cur[d], 1u);
        eidx[slot] = pos;
        snrm[pos] = 1.0f / fmaxf((float)dg[d], 1.0f);
    }
}

// ---------------- all dtype-convert preps fused into one kernel ----------------
namespace {
constexpr int NX_  = 5 * N_NODES * FIN;
constexpr int NW1_ = 5 * RREL * FIN * H1S;
constexpr int NW2_ = 5 * RREL * H1S * H2S;
constexpr int NM1_ = 256 * 576;
constexpr int NM2_ = 128 * 256;
constexpr int NM3_ = 128 * 128;
constexpr int NPREP = NX_ + NW1_ + NW2_ + NM1_ + NM2_ + NM3_;
}
__global__ __launch_bounds__(256) void prep_all(const float* __restrict__ x_o,
                                                const float* __restrict__ x_s,
                                                const float* __restrict__ W1,
                                                const float* __restrict__ Ws1,
                                                const float* __restrict__ W2,
                                                const float* __restrict__ Ws2,
                                                const float* __restrict__ mw1,
                                                const float* __restrict__ mw2,
                                                const float* __restrict__ mw3,
                                                u16* __restrict__ xbf,
                                                u16* __restrict__ wt1,
                                                u16* __restrict__ wt2,
                                                u16* __restrict__ w1t,
                                                u16* __restrict__ w2t,
                                                u16* __restrict__ w3t) {
    int t = blockIdx.x * 256 + threadIdx.x;
    if (t < NX_) {
        int g = t / (N_NODES * FIN), off = t % (N_NODES * FIN);
        float v = (g == 0) ? x_o[off] : x_s[(size_t)(g - 1) * N_NODES * FIN + off];
        xbf[t] = f2bf(v);
        return;
    }
    t -= NX_;
    if (t < NW1_) {
        int q = t % (RREL * FIN * H1S), g = t / (RREL * FIN * H1S);
        int k = q & 127; int ro = q >> 7; int o = ro & 63; int r = ro >> 6;
        const float* src = (g == 0) ? W1 : Ws1 + (size_t)(g - 1) * RREL * FIN * H1S;
        wt1[(size_t)g * RREL * FIN * H1S + q] = f2bf(src[((size_t)r * FIN + k) * H1S + o]);
        return;
    }
    t -= NW1_;
    if (t < NW2_) {
        int q = t % (RREL * H1S * H2S), g = t / (RREL * H1S * H2S);
        int k = q & 63; int ro = q >> 6; int o = ro & 31; int r = ro >> 5;
        const float* src = (g == 0) ? W2 : Ws2 + (size_t)(g - 1) * RREL * H1S * H2S;
        wt2[(size_t)g * RREL * H1S * H2S + q] = f2bf(src[((size_t)r * H1S + k) * H2S + o]);
        return;
    }
    t -= NW2_;
    if (t < NM1_) {
        int k = t % 576, o = t / 576;
        w1t[t] = f2bf(mw1[(size_t)k * 256 + o]);
        return;
    }
    t -= NM1_;
    if (t < NM2_) {
        int k = t % 256, o = t / 256;
        w2t[t] = f2bf(mw2[(size_t)k * 128 + o]);
        return;
    }
    t -= NM2_;
    if (t < NM3_) {
        int k = t % 128, o = t / 128;
        w3t[t] = (o < 65) ? f2bf(mw3[(size_t)k * 65 + o]) : (u16)0;
    }
}

// ---------------- layer-1 MFMA message GEMM, all graphs ----------------
__global__ __launch_bounds__(256) void rgcn_mfma_l1_all(const u16* __restrict__ xbfa,
                                                        const int* __restrict__ ssrc,
                                                        const float* __restrict__ snrm,
                                                        const int* __restrict__ c2r,
                                                        const u16* __restrict__ wt1a,
                                                        u16* __restrict__ medge) {
    __shared__ uint4 Xs4[128 * 16];
    __shared__ uint4 Wt4[64 * 16];
    int tid = threadIdx.x;
    int bid = xcd_swz(blockIdx.x);
    int r = c2r[bid];
    if (r < 0) return;
    int g = chunk_graph(bid);
    int e0 = bid * 128;
    const u16* xbf = xbfa + (size_t)g * N_NODES * FIN;
    {
        const uint4* wsrc = (const uint4*)(wt1a + ((size_t)g * RREL + r) * H1S * FIN);
        #pragma unroll
        for (int i = 0; i < 4; ++i) {
            int g16 = tid + i * 256;
            int row = g16 >> 4, c = g16 & 15;
            Wt4[row * 16 + (c ^ (row & 7))] = wsrc[g16];
        }
    }
    {
        int rt = tid >> 1, h = tid & 1;
        int s = ssrc[e0 + rt];
        const uint4* src = (const uint4*)(xbf + (size_t)s * FIN) + h * 8;
        #pragma unroll
        for (int j = 0; j < 8; ++j) {
            int c = h * 8 + j;
            Xs4[rt * 16 + (c ^ (rt & 7))] = src[j];
        }
    }
    __syncthreads();
    int w = tid >> 6, l = tid & 63;
    int lo = l & 15, hi = l >> 4;
    f32x4 acc[2][4];
    #pragma unroll
    for (int m = 0; m < 2; ++m)
        #pragma unroll
        for (int n = 0; n < 4; ++n) acc[m][n] = {0.f, 0.f, 0.f, 0.f};
    #pragma unroll
    for (int kk = 0; kk < 4; ++kk) {
        int kc = kk * 4 + hi;
        int ea = w * 32 + lo, eb = ea + 16;
        bf16x8 a0 = as_bf16x8(Xs4[ea * 16 + (kc ^ (ea & 7))]);
        bf16x8 a1 = as_bf16x8(Xs4[eb * 16 + (kc ^ (eb & 7))]);
        #pragma unroll
        for (int n = 0; n < 4; ++n) {
            int o = n * 16 + lo;
            bf16x8 b = as_bf16x8(Wt4[o * 16 + (kc ^ (o & 7))]);
            acc[0][n] = __builtin_amdgcn_mfma_f32_16x16x32_bf16(a0, b, acc[0][n], 0, 0, 0);
            acc[1][n] = __builtin_amdgcn_mfma_f32_16x16x32_bf16(a1, b, acc[1][n], 0, 0, 0);
        }
    }
    #pragma unroll
    for (int m = 0; m < 2; ++m) {
        #pragma unroll
        for (int rg = 0; rg < 4; ++rg) {
            int erow = e0 + w * 32 + m * 16 + hi * 4 + rg;
            float nv = snrm[erow];
            if (nv != 0.f) {
                size_t jb = (size_t)erow * H1S;
                #pragma unroll
                for (int n = 0; n < 4; ++n)
                    medge[jb + n * 16 + lo] = f2bf(acc[m][n][rg] * nv);
            }
        }
    }
}

// ---------------- layer-2 MFMA message GEMM, all graphs ----------------
__global__ __launch_bounds__(256) void rgcn_mfma_l2_all(const u16* __restrict__ h1bfa,
                                                        const int* __restrict__ ssrc,
                                                        const float* __restrict__ snrm,
                                                        const int* __restrict__ c2r,
                                                        const u16* __restrict__ wt2a,
                                                        u16* __restrict__ medge) {
    __shared__ uint4 Xs4[128 * 8];
    __shared__ uint4 Wt4[32 * 8];
    int tid = threadIdx.x;
    int bid = xcd_swz(blockIdx.x);
    int r = c2r[bid];
    if (r < 0) return;
    int g = chunk_graph(bid);
    int e0 = bid * 128;
    const u16* h1bf = h1bfa + (size_t)g * N_NODES * H1S;
    {
        const uint4* wsrc = (const uint4*)(wt2a + ((size_t)g * RREL + r) * H2S * H1S);
        int row = tid >> 3, c = tid & 7;
        Wt4[row * 8 + (c ^ (row & 7))] = wsrc[tid];
    }
    {
        int rt = tid >> 1, h = tid & 1;
        int s = ssrc[e0 + rt];
        const uint4* src = (const uint4*)(h1bf + (size_t)s * H1S) + h * 4;
        #pragma unroll
        for (int j = 0; j < 4; ++j) {
            int c = h * 4 + j;
            Xs4[rt * 8 + (c ^ (rt & 7))] = src[j];
        }
    }
    __syncthreads();
    int w = tid >> 6, l = tid & 63;
    int lo = l & 15, hi = l >> 4;
    f32x4 acc[2][2];
    #pragma unroll
    for (int m = 0; m < 2; ++m)
        #pragma unroll
        for (int n = 0; n < 2; ++n) acc[m][n] = {0.f, 0.f, 0.f, 0.f};
    #pragma unroll
    for (int kk = 0; kk < 2; ++kk) {
        int kc = kk * 4 + hi;
        int ea = w * 32 + lo, eb = ea + 16;
        bf16x8 a0 = as_bf16x8(Xs4[ea * 8 + (kc ^ (ea & 7))]);
        bf16x8 a1 = as_bf16x8(Xs4[eb * 8 + (kc ^ (eb & 7))]);
        #pragma unroll
        for (int n = 0; n < 2; ++n) {
            int o = n * 16 + lo;
            bf16x8 b = as_bf16x8(Wt4[o * 8 + (kc ^ (o & 7))]);
            acc[0][n] = __builtin_amdgcn_mfma_f32_16x16x32_bf16(a0, b, acc[0][n], 0, 0, 0);
            acc[1][n] = __builtin_amdgcn_mfma_f32_16x16x32_bf16(a1, b, acc[1][n], 0, 0, 0);
        }
    }
    #pragma unroll
    for (int m = 0; m < 2; ++m) {
        #pragma unroll
        for (int rg = 0; rg < 4; ++rg) {
            int erow = e0 + w * 32 + m * 16 + hi * 4 + rg;
            float nv = snrm[erow];
            if (nv != 0.f) {
                size_t jb = (size_t)erow * H2S;
                #pragma unroll
                for (int n = 0; n < 2; ++n)
                    medge[jb + n * 16 + lo] = f2bf(acc[m][n][rg] * nv);
            }
        }
    }
}

// ---------------- fused gather + finish, layer 1 (8-wide pipelined gather) -------
__global__ __launch_bounds__(256) void finish_l1_all(const float* __restrict__ x_o,
                                                     const float* __restrict__ x_s,
                                                     const float* __restrict__ root1,
                                                     const float* __restrict__ roots1,
                                                     const float* __restrict__ b1,
                                                     const float* __restrict__ bs1,
                                                     const u16* __restrict__ medge,
                                                     const int* __restrict__ row_ptr,
                                                     const int* __restrict__ eidx,
                                                     float* __restrict__ aggH1,
                                                     u16* __restrict__ h1bfa) {
    int g = blockIdx.y;
    const float* x    = (g == 0) ? x_o : x_s + (size_t)(g - 1) * N_NODES * FIN;
    const float* root = (g == 0) ? root1 : roots1 + (size_t)(g - 1) * FIN * H1S;
    const float* bias = (g == 0) ? b1 : bs1 + (size_t)(g - 1) * H1S;
    const int* rp = row_ptr + (size_t)g * (N_NODES + 1);
    float* h1 = aggH1 + (size_t)g * N_NODES * H1S;
    u16* h1bf = h1bfa + (size_t)g * N_NODES * H1S;
    __shared__ float xs[16][FIN + 1];
    int tid = threadIdx.x;
    int vsub = tid >> 4, og = tid & 15;
    int v = blockIdx.x * 16 + vsub;
    bool valid = v < N_NODES;
    int vv = valid ? v : N_NODES - 1;
    #pragma unroll
    for (int i = 0; i < 8; ++i)
        xs[vsub][og + 16 * i] = x[(size_t)vv * FIN + og + 16 * i];
    int j0 = rp[vv], j1 = rp[vv + 1];
    float4 acc;
    acc.x = bias[og * 4 + 0]; acc.y = bias[og * 4 + 1];
    acc.z = bias[og * 4 + 2]; acc.w = bias[og * 4 + 3];
    int j = j0;
    for (; j + 8 <= j1; j += 8) {
        int p[8];
        #pragma unroll
        for (int q = 0; q < 8; ++q) p[q] = eidx[j + q];
        u64 mm[8];
        #pragma unroll
        for (int q = 0; q < 8; ++q)
            mm[q] = *(const u64*)(medge + (size_t)p[q] * H1S + og * 4);
        #pragma unroll
        for (int q = 0; q < 8; ++q) {
            u32 mlo = (u32)mm[q], mhi = (u32)(mm[q] >> 32);
            acc.x += bf2f_lo(mlo); acc.y += bf2f_hi(mlo);
            acc.z += bf2f_lo(mhi); acc.w += bf2f_hi(mhi);
        }
    }
    for (; j < j1; ++j) {
        int pos = eidx[j];
        u64 m = *(const u64*)(medge + (size_t)pos * H1S + og * 4);
        u32 mlo = (u32)m, mhi = (u32)(m >> 32);
        acc.x += bf2f_lo(mlo); acc.y += bf2f_hi(mlo);
        acc.z += bf2f_lo(mhi); acc.w += bf2f_hi(mhi);
    }
    __syncthreads();
    const float* Rp = root + og * 4;
    #pragma unroll 16
    for (int i = 0; i < FIN; ++i) {
        float xv = xs[vsub][i];
        float4 w = *(const float4*)(Rp + (size_t)i * H1S);
        acc.x += xv * w.x; acc.y += xv * w.y; acc.z += xv * w.z; acc.w += xv * w.w;
    }
    if (valid) {
        float r0 = fmaxf(acc.x, 0.f), r1 = fmaxf(acc.y, 0.f);
        float r2 = fmaxf(acc.z, 0.f), r3 = fmaxf(acc.w, 0.f);
        float* ag = h1 + (size_t)vv * H1S + og * 4;
        ag[0] = r0; ag[1] = r1; ag[2] = r2; ag[3] = r3;
        uint2 pk;
        pk.x = (u32)f2bf(r0) | ((u32)f2bf(r1) << 16);
        pk.y = (u32)f2bf(r2) | ((u32)f2bf(r3) << 16);
        *(uint2*)(h1bf + (size_t)vv * H1S + og * 4) = pk;
    }
}

// ---------------- fused gather + finish, layer 2 (8-wide pipelined gather) -------
__global__ __launch_bounds__(256) void finish_l2_all(const float* __restrict__ aggH1,
                                                     const float* __restrict__ root2,
                                                     const float* __restrict__ roots2,
                                                     const float* __restrict__ b2,
                                                     const float* __restrict__ bs2,
                                                     const u16* __restrict__ medge,
                                                     const int* __restrict__ row_ptr,
                                                     const int* __restrict__ eidx,
                                                     float* __restrict__ aggH2) {
    int g = blockIdx.y;
    const float* x    = aggH1 + (size_t)g * N_NODES * H1S;
    const float* root = (g == 0) ? root2 : roots2 + (size_t)(g - 1) * H1S * H2S;
    const float* bias = (g == 0) ? b2 : bs2 + (size_t)(g - 1) * H2S;
    const int* rp = row_ptr + (size_t)g * (N_NODES + 1);
    float* x2 = aggH2 + (size_t)g * N_NODES * H2S;
    __shared__ float xs[32][H1S + 1];
    int tid = threadIdx.x;
    int vsub = tid >> 3, og = tid & 7;
    int v = blockIdx.x * 32 + vsub;
    bool valid = v < N_NODES;
    int vv = valid ? v : N_NODES - 1;
    #pragma unroll
    for (int i = 0; i < 8; ++i)
        xs[vsub][og + 8 * i] = x[(size_t)vv * H1S + og + 8 * i];
    int j0 = rp[vv], j1 = rp[vv + 1];
    float4 acc;
    acc.x = bias[og * 4 + 0]; acc.y = bias[og * 4 + 1];
    acc.z = bias[og * 4 + 2]; acc.w = bias[og * 4 + 3];
    int j = j0;
    for (; j + 8 <= j1; j += 8) {
        int p[8];
        #pragma unroll
        for (int q = 0; q < 8; ++q) p[q] = eidx[j + q];
        u64 mm[8];
        #pragma unroll
        for (int q = 0; q < 8; ++q)
            mm[q] = *(const u64*)(medge + (size_t)p[q] * H2S + og * 4);
        #pragma unroll
        for (int q = 0; q < 8; ++q) {
            u32 mlo = (u32)mm[q], mhi = (u32)(mm[q] >> 32);
            acc.x += bf2f_lo(mlo); acc.y += bf2f_hi(mlo);
            acc.z += bf2f_lo(mhi); acc.w += bf2f_hi(mhi);
        }
    }
    for (; j < j1; ++j) {
        int pos = eidx[j];
        u64 m = *(const u64*)(medge + (size_t)pos * H2S + og * 4);
        u32 mlo = (u32)m, mhi = (u32)(m >> 32);
        acc.x += bf2f_lo(mlo); acc.y += bf2f_hi(mlo);
        acc.z += bf2f_lo(mhi); acc.w += bf2f_hi(mhi);
    }
    __syncthreads();
    const float* Rp = root + og * 4;
    #pragma unroll
    for (int i = 0; i < H1S; ++i) {
        float xv = xs[vsub][i];
        float4 w = *(const float4*)(Rp + (size_t)i * H2S);
        acc.x += xv * w.x; acc.y += xv * w.y; acc.z += xv * w.z; acc.w += xv * w.w;
    }
    if (valid) {
        float* ag = x2 + (size_t)vv * H2S + og * 4;
        ag[0] = acc.x; ag[1] = acc.y; ag[2] = acc.z; ag[3] = acc.w;
    }
}

// ---------------- gather pair features -> bf16 ----------------
__global__ __launch_bounds__(256) void gather_feats_direct(const float* __restrict__ aggH2,
                                                           const float* __restrict__ features1,
                                                           const int* __restrict__ idx,
                                                           u16* __restrict__ featsbf) {
    int t = blockIdx.x * blockDim.x + threadIdx.x;
    if (t >= BP * 576) return;
    int b = t / 576, c = t % 576;
    int d1 = idx[b], d2 = idx[BP + b];
    float v;
    if (c < 160) {
        int bb = c >> 5, cc = c & 31;
        v = aggH2[(size_t)bb * N_NODES * H2S + (size_t)d1 * H2S + cc];
    } else if (c < 288) {
        v = features1[(size_t)d1 * FIN + (c - 160)];
    } else if (c < 448) {
        int cc2 = c - 288;
        int bb = cc2 >> 5, cc = cc2 & 31;
        v = aggH2[(size_t)bb * N_NODES * H2S + (size_t)d2 * H2S + cc];
    } else {
        v = features1[(size_t)d2 * FIN + (c - 448)];
    }
    featsbf[t] = f2bf(v);
}

// ---------------- MLP MFMA GEMM ----------------
template <int ACT, int OUTF>
__global__ __launch_bounds__(256) void mlp_mfma(const u16* __restrict__ A,
                                                const u16* __restrict__ Bt,
                                                const float* __restrict__ bias,
                                                u16* __restrict__ Cbf,
                                                float* __restrict__ Cf,
                                                int M, int N, int K) {
    __shared__ uint4 As4[128 * 8];
    __shared__ uint4 Bs4[64 * 8];
    int tid = threadIdx.x;
    int row0 = blockIdx.x * 128, col0 = blockIdx.y * 64;
    int w = tid >> 6, l = tid & 63;
    int lo = l & 15, hi = l >> 4;
    f32x4 acc[2][4];
    #pragma unroll
    for (int m = 0; m < 2; ++m)
        #pragma unroll
        for (int n = 0; n < 4; ++n) acc[m][n] = {0.f, 0.f, 0.f, 0.f};
    int nchunks = K >> 6;
    for (int ch = 0; ch < nchunks; ++ch) {
        #pragma unroll
        for (int i = 0; i < 4; ++i) {
            int g16 = tid + i * 256;
            int rr = g16 >> 3, c = g16 & 7;
            As4[rr * 8 + (c ^ (rr & 7))] =
                *((const uint4*)(A + (size_t)(row0 + rr) * K + ch * 64) + c);
        }
        #pragma unroll
        for (int i = 0; i < 2; ++i) {
            int g16 = tid + i * 256;
            int rr = g16 >> 3, c = g16 & 7;
            Bs4[rr * 8 + (c ^ (rr & 7))] =
                *((const uint4*)(Bt + (size_t)(col0 + rr) * K + ch * 64) + c);
        }
        __syncthreads();
        #pragma unroll
        for (int ks = 0; ks < 2; ++ks) {
            int kc = ks * 4 + hi;
            int ra = w * 32 + lo, rb = w * 32 + 16 + lo;
            bf16x8 a0 = as_bf16x8(As4[ra * 8 + (kc ^ (ra & 7))]);
            bf16x8 a1 = as_bf16x8(As4[rb * 8 + (kc ^ (rb & 7))]);
            #pragma unroll
            for (int n = 0; n < 4; ++n) {
                int o = n * 16 + lo;
                bf16x8 b = as_bf16x8(Bs4[o * 8 + (kc ^ (o & 7))]);
                acc[0][n] = __builtin_amdgcn_mfma_f32_16x16x32_bf16(a0, b, acc[0][n], 0, 0, 0);
                acc[1][n] = __builtin_amdgcn_mfma_f32_16x16x32_bf16(a1, b, acc[1][n], 0, 0, 0);
            }
        }
        __syncthreads();
    }
    #pragma unroll
    for (int m = 0; m < 2; ++m) {
        #pragma unroll
        for (int rg = 0; rg < 4; ++rg) {
            int rr = row0 + w * 32 + m * 16 + hi * 4 + rg;
            if (rr < M) {
                #pragma unroll
                for (int n = 0; n < 4; ++n) {
                    int cc = col0 + n * 16 + lo;
                    if (cc < N) {
                        float v = acc[m][n][rg] + bias[cc];
                        if (ACT == 1) v = (v > 0.f) ? v : expm1f(v);
                        if (OUTF) Cf[(size_t)rr * N + cc] = v;
                        else Cbf[(size_t)rr * N + cc] = f2bf(v);
                    }
                }
            }
        }
    }
}

extern "C" void kernel_launch(void* const* d_in, const int* in_sizes, int n_in,
                              void* d_out, int out_size, void* d_ws, size_t ws_size,
                              hipStream_t stream) {
    const float* x_o      = (const float*)d_in[0];
    const int*   ei_o     = (const int*)d_in[1];
    const int*   et_o     = (const int*)d_in[2];
    const float* x_s      = (const float*)d_in[3];
    const int*   ei_s     = (const int*)d_in[4];
    const int*   et_s     = (const int*)d_in[5];
    const int*   idx      = (const int*)d_in[6];
    const float* features1= (const float*)d_in[7];
    const float* W1       = (const float*)d_in[8];
    const float* root1    = (const float*)d_in[9];
    const float* b1       = (const float*)d_in[10];
    const float* W2       = (const float*)d_in[11];
    const float* root2    = (const float*)d_in[12];
    const float* b2       = (const float*)d_in[13];
    const float* Ws1      = (const float*)d_in[14];
    const float* roots1   = (const float*)d_in[15];
    const float* bs1      = (const float*)d_in[16];
    const float* Ws2      = (const float*)d_in[17];
    const float* roots2   = (const float*)d_in[18];
    const float* bs2      = (const float*)d_in[19];
    const float* mlp_w1   = (const float*)d_in[20];
    const float* mlp_b1   = (const float*)d_in[21];
    const float* mlp_w2   = (const float*)d_in[22];
    const float* mlp_b2   = (const float*)d_in[23];
    const float* mlp_w3   = (const float*)d_in[24];
    const float* mlp_b3   = (const float*)d_in[25];

    // ---- workspace layout (zeroed region FIRST) ----
    int*   hist     = (int*)d_ws;                                // 5*R      [zero]
    int*   ssrc     = hist + 5 * RREL;                           // CAP_TOT  [zero]
    float* snrm     = (float*)(ssrc + CAP_TOT);                  // CAP_TOT  [zero]
    // ---- end zero region ----
    int*   sdst     = (int*)(snrm + CAP_TOT);                    // CAP_TOT
    int*   cursor   = sdst + CAP_TOT;                            // 5*R
    int*   relbase  = cursor + 5 * RREL;                         // 5*R
    int*   c2r      = relbase + 5 * RREL;                        // CHK_TOT_PAD
    u32*   deg_r    = (u32*)(c2r + CHK_TOT_PAD);                 // 5*R*N
    u32*   base_abs = deg_r + (size_t)5 * RREL * N_NODES;        // 5*R*N
    int*   node_deg = (int*)(base_abs + (size_t)5 * RREL * N_NODES); // 5*N
    int*   row_ptr  = node_deg + 5 * N_NODES;                    // 5*(N+1)
    int*   eidx     = row_ptr + 5 * (N_NODES + 1);               // E_TOT
    float* aggH1    = (float*)(eidx + E_TOT);                    // 5*N*64
    float* aggH2    = aggH1 + (size_t)5 * N_NODES * H1S;         // 5*N*32
    u16*   featsbf  = (u16*)(aggH2 + (size_t)5 * N_NODES * H2S); // B*576
    u16*   mh1bf    = featsbf + (size_t)BP * 576;                // B*256
    u16*   mh2bf    = mh1bf + (size_t)BP * 256;                  // B*128
    u16*   w1t      = mh2bf + (size_t)BP * 128;                  // 256*576
    u16*   w2t      = w1t + (size_t)256 * 576;                   // 128*256
    u16*   w3t      = w2t + (size_t)128 * 256;                   // 128*128
    u16*   wt1a     = w3t + (size_t)128 * 128;                   // 5*R*64*128
    u16*   wt2a     = wt1a + (size_t)5 * RREL * H1S * FIN;       // 5*R*32*64
    u16*   xbfa     = wt2a + (size_t)5 * RREL * H2S * H1S;       // 5*N*128
    u16*   h1bfa    = xbfa + (size_t)5 * N_NODES * FIN;          // 5*N*64
    u16*   medge    = h1bfa + (size_t)5 * N_NODES * H1S;         // CAP_TOT*64

    size_t zero_bytes = (size_t)((char*)sdst - (char*)d_ws);
    hipMemsetAsync(d_ws, 0, zero_bytes, stream);

    // ---- preprocessing ----
    prep_all<<<(NPREP + 255) / 256, 256, 0, stream>>>(
        x_o, x_s, W1, Ws1, W2, Ws2, mlp_w1, mlp_w2, mlp_w3,
        xbfa, wt1a, wt2a, w1t, w2t, w3t);
    count_hist_all<<<dim3(128, 5), 256, 0, stream>>>(et_o, et_s, hist);
    prefix_fill<<<5, 256, 0, stream>>>(hist, cursor, relbase, c2r);
    scatter_rel<<<dim3(SBLK_MAIN, 5), 256, 0, stream>>>(
        ei_o, et_o, ei_s, et_s, cursor, ssrc, sdst);
    seg_hist<<<dim3(RREL, 5), 256, 0, stream>>>(sdst, relbase, hist, deg_r);
    nodedeg_from_degr<<<(5 * N_NODES + 255) / 256, 256, 0, stream>>>(deg_r, node_deg);
    scan_rowptr<<<5, 256, 0, stream>>>(node_deg, row_ptr);
    drbase<<<(5 * N_NODES + 255) / 256, 256, 0, stream>>>(deg_r, row_ptr, base_abs);
    snrm_eidx<<<dim3(RREL, 5), 256, 0, stream>>>(
        sdst, relbase, hist, base_abs, deg_r, eidx, snrm);

    // ---- encoders ----
    rgcn_mfma_l1_all<<<CHK_TOT, 256, 0, stream>>>(
        xbfa, ssrc, snrm, c2r, wt1a, medge);
    finish_l1_all<<<dim3((N_NODES + 15) / 16, 5), 256, 0, stream>>>(
        x_o, x_s, root1, roots1, b1, bs1, medge, row_ptr, eidx, aggH1, h1bfa);
    rgcn_mfma_l2_all<<<CHK_TOT, 256, 0, stream>>>(
        h1bfa, ssrc, snrm, c2r, wt2a, medge);
    finish_l2_all<<<dim3((N_NODES + 31) / 32, 5), 256, 0, stream>>>(
        aggH1, root2, roots2, b2, bs2, medge, row_ptr, eidx, aggH2);

    // ---- head ----
    gather_feats_direct<<<(BP * 576 + 255) / 256, 256, 0, stream>>>(aggH2, features1, idx, featsbf);
    mlp_mfma<1, 0><<<dim3(BP / 128, 4), 256, 0, stream>>>(featsbf, w1t, mlp_b1, mh1bf, nullptr, BP, 256, 576);
    mlp_mfma<1, 0><<<dim3(BP / 128, 2), 256, 0, stream>>>(mh1bf, w2t, mlp_b2, mh2bf, nullptr, BP, 128, 256);
    mlp_mfma<0, 1><<<dim3(BP / 128, 2), 256, 0, stream>>>(mh2bf, w3t, mlp_b3, nullptr, (float*)d_out, BP, 65, 128);
}